// Round 2
// baseline (414.906 us; speedup 1.0000x reference)
//
#include <hip/hip_runtime.h>

#define HH 128
#define WW 128
#define CC 64
#define ROW (WW*CC)          // 8192 elements per (b,h) row
#define PADW 72              // f16 elems per pixel slot in conv LDS (byte stride 144 = 16*9)
#define LSTR 66              // diffuse LDS row stride (floats); pad breaks 4-bank aliasing

typedef _Float16 half8 __attribute__((ext_vector_type(8)));
typedef _Float16 half4v __attribute__((ext_vector_type(4)));
typedef float floatx4 __attribute__((ext_vector_type(4)));

// ---------------------------------------------------------------------------
// Repack HWIO fp32 weights [3][3][64][64] -> f16 B-frag layout:
// W2[(step*4+q)*512 + o*8 + j] = W[tap][kc*32+q*8+j][o], step = tap*2+kc
// ---------------------------------------------------------------------------
__global__ __launch_bounds__(256)
void repack_w(const float* __restrict__ wf, const float* __restrict__ wg,
              _Float16* __restrict__ W2f, _Float16* __restrict__ W2g)
{
    int idx = blockIdx.x * 256 + threadIdx.x;      // 0..73727
    int sel = idx >= 36864;
    int id  = sel ? idx - 36864 : idx;             // (t*64 + c)*64 + o
    const float* src = sel ? wg : wf;
    _Float16* dst = sel ? W2g : W2f;
    int t = id >> 12, c = (id >> 6) & 63, o = id & 63;
    int kc = c >> 5, q = (c >> 3) & 3, j = c & 7;
    int pos = ((((t*2 + kc)*4 + q)*64 + o) << 3) + j;
    dst[pos] = (_Float16)src[id];
}

// ---------------------------------------------------------------------------
// Implicit-GEMM 3x3 SAME conv via f16 MFMA.  (unchanged from R6 - verified)
// Block = 2 output rows (b, i0..i0+1). LDS: 4 input rows, 130 px slots, PADW.
// Wave = 64 px x 64 couts: acc[4][4], 16 MFMAs per 4 B-frag loads.
// Epilogue restages fp32 acc through LDS -> lane-contiguous vector stores.
// XCD-bijective swizzle (1024 = 8 x 128) for halo-row L2 locality.
// ---------------------------------------------------------------------------
template<int BNIN, int EPI>
__global__ __launch_bounds__(256, 2)
void conv_mfma(const void* __restrict__ srcv, const _Float16* __restrict__ W2,
               _Float16* __restrict__ outH, float* __restrict__ outF,
               _Float16* __restrict__ y2,
               const float* __restrict__ ig, const float* __restrict__ ib,
               const float* __restrict__ imu, const float* __restrict__ iva,
               const float* __restrict__ og, const float* __restrict__ ob,
               const float* __restrict__ om, const float* __restrict__ ov)
{
    __shared__ __align__(16) _Float16 sIn[4*130*PADW];   // 74880 B -> 2 blocks/CU
    const int t = threadIdx.x;
    const int blk = ((blockIdx.x & 7) << 7) | (blockIdx.x >> 3);  // XCD swizzle
    const int b = blk >> 6, i0 = (blk & 63) * 2;

    // per-thread BN constants for staging (c8 = (t&7)*8 is k-invariant)
    const int c8 = (t & 7) << 3;
    float scv[8], biv[8];
    if (BNIN) {
        #pragma unroll
        for (int j = 0; j < 8; ++j) {
            float s = ig[c8+j] * rsqrtf(iva[c8+j] + 1e-3f);
            scv[j] = s; biv[j] = ib[c8+j] - imu[c8+j]*s;
        }
    }

    // stage 4 input rows (i0-1 .. i0+2)
    for (int r = 0; r < 4; ++r) {
        int iy = i0 - 1 + r;
        bool inb = (iy >= 0) && (iy < HH);
        #pragma unroll
        for (int k = 0; k < 4; ++k) {
            int idx = t + (k << 8);
            int px = idx >> 3;
            half8 v = {0,0,0,0,0,0,0,0};
            if (inb) {
                if (BNIN) {
                    const float* gp = (const float*)srcv
                        + ((size_t)(b*HH + iy))*ROW + px*CC + c8;
                    float4 u0 = *(const float4*)gp;
                    float4 u1 = *(const float4*)(gp + 4);
                    v[0] = (_Float16)fmaxf(0.f, u0.x*scv[0] + biv[0]);
                    v[1] = (_Float16)fmaxf(0.f, u0.y*scv[1] + biv[1]);
                    v[2] = (_Float16)fmaxf(0.f, u0.z*scv[2] + biv[2]);
                    v[3] = (_Float16)fmaxf(0.f, u0.w*scv[3] + biv[3]);
                    v[4] = (_Float16)fmaxf(0.f, u1.x*scv[4] + biv[4]);
                    v[5] = (_Float16)fmaxf(0.f, u1.y*scv[5] + biv[5]);
                    v[6] = (_Float16)fmaxf(0.f, u1.z*scv[6] + biv[6]);
                    v[7] = (_Float16)fmaxf(0.f, u1.w*scv[7] + biv[7]);
                } else {
                    v = *(const half8*)((const _Float16*)srcv
                        + ((size_t)(b*HH + iy))*ROW + px*CC + c8);
                }
            }
            *(half8*)(sIn + (r*130 + px + 1)*PADW + c8) = v;
        }
    }
    // zero edge pixel slots (0 and 129) x 4 rows
    if (t < 128) {
        int rr = t >> 5, s = (t >> 4) & 1, c4 = (t & 15) << 2;
        int slot = s ? 129 : 0;
        half4v z = {0,0,0,0};
        *(half4v*)(sIn + (rr*130 + slot)*PADW + c4) = z;
    }
    __syncthreads();

    const int wv = t >> 6, lane = t & 63;
    const int lm = lane & 15, quad = lane >> 4;
    const int r  = wv >> 1;                        // local output row 0/1
    const int px0 = (wv & 1) * 64;
    floatx4 z4 = {0.f,0.f,0.f,0.f};
    floatx4 acc[4][4];
    #pragma unroll
    for (int ms = 0; ms < 4; ++ms)
        #pragma unroll
        for (int nt = 0; nt < 4; ++nt) acc[ms][nt] = z4;

    #pragma unroll
    for (int tap = 0; tap < 9; ++tap) {
        const int di = tap / 3, dj = tap % 3;
        #pragma unroll
        for (int kc = 0; kc < 2; ++kc) {
            const _Float16* ab = sIn + ((r + di)*130 + px0 + lm + dj)*PADW
                               + kc*32 + quad*8;
            half8 a0 = *(const half8*)(ab);
            half8 a1 = *(const half8*)(ab + 16*PADW);
            half8 a2 = *(const half8*)(ab + 32*PADW);
            half8 a3 = *(const half8*)(ab + 48*PADW);
            const _Float16* wb = W2 + (((tap*2 + kc)*4 + quad) << 9) + (lm << 3);
            half8 b0 = *(const half8*)(wb);
            half8 b1 = *(const half8*)(wb + 128);
            half8 b2 = *(const half8*)(wb + 256);
            half8 b3 = *(const half8*)(wb + 384);
            acc[0][0] = __builtin_amdgcn_mfma_f32_16x16x32_f16(a0, b0, acc[0][0], 0,0,0);
            acc[1][0] = __builtin_amdgcn_mfma_f32_16x16x32_f16(a1, b0, acc[1][0], 0,0,0);
            acc[2][0] = __builtin_amdgcn_mfma_f32_16x16x32_f16(a2, b0, acc[2][0], 0,0,0);
            acc[3][0] = __builtin_amdgcn_mfma_f32_16x16x32_f16(a3, b0, acc[3][0], 0,0,0);
            acc[0][1] = __builtin_amdgcn_mfma_f32_16x16x32_f16(a0, b1, acc[0][1], 0,0,0);
            acc[1][1] = __builtin_amdgcn_mfma_f32_16x16x32_f16(a1, b1, acc[1][1], 0,0,0);
            acc[2][1] = __builtin_amdgcn_mfma_f32_16x16x32_f16(a2, b1, acc[2][1], 0,0,0);
            acc[3][1] = __builtin_amdgcn_mfma_f32_16x16x32_f16(a3, b1, acc[3][1], 0,0,0);
            acc[0][2] = __builtin_amdgcn_mfma_f32_16x16x32_f16(a0, b2, acc[0][2], 0,0,0);
            acc[1][2] = __builtin_amdgcn_mfma_f32_16x16x32_f16(a1, b2, acc[1][2], 0,0,0);
            acc[2][2] = __builtin_amdgcn_mfma_f32_16x16x32_f16(a2, b2, acc[2][2], 0,0,0);
            acc[3][2] = __builtin_amdgcn_mfma_f32_16x16x32_f16(a3, b2, acc[3][2], 0,0,0);
            acc[0][3] = __builtin_amdgcn_mfma_f32_16x16x32_f16(a0, b3, acc[0][3], 0,0,0);
            acc[1][3] = __builtin_amdgcn_mfma_f32_16x16x32_f16(a1, b3, acc[1][3], 0,0,0);
            acc[2][3] = __builtin_amdgcn_mfma_f32_16x16x32_f16(a2, b3, acc[2][3], 0,0,0);
            acc[3][3] = __builtin_amdgcn_mfma_f32_16x16x32_f16(a3, b3, acc[3][3], 0,0,0);
        }
    }

    // ---- epilogue: restage fp32 acc -> LDS [256 px][64 c], then vector copy-out
    __syncthreads();                               // all A-frag reads done
    float* sF = (float*)sIn;                       // 64 KB of the 74880 B
    #pragma unroll
    for (int nt = 0; nt < 4; ++nt) {
        int c = nt*16 + lm;
        #pragma unroll
        for (int ms = 0; ms < 4; ++ms) {
            int pix = r*128 + px0 + ms*16 + quad*4;
            floatx4 v = acc[ms][nt];
            #pragma unroll
            for (int rv = 0; rv < 4; ++rv)
                sF[(pix + rv)*64 + c] = v[rv];
        }
    }
    __syncthreads();

    const size_t gbase = ((size_t)(b*HH + i0)) * ROW;   // 2 contiguous rows
    if (EPI) {
        const int c8o = (t & 7) << 3;             // elem%64 of (jj*256+t)*8
        float s8[8], bb8[8];
        #pragma unroll
        for (int j = 0; j < 8; ++j) {
            float ss = og[c8o+j] * rsqrtf(ov[c8o+j] + 1e-3f);
            s8[j] = ss; bb8[j] = ob[c8o+j] - om[c8o+j]*ss;
        }
        #pragma unroll
        for (int jj = 0; jj < 8; ++jj) {
            int e = (jj*256 + t) << 3;            // 0..16383, lane-contiguous
            floatx4 u0 = *(const floatx4*)(sF + e);
            floatx4 u1 = *(const floatx4*)(sF + e + 4);
            half8 hv, yv;
            #pragma unroll
            for (int j = 0; j < 4; ++j) {
                hv[j]   = (_Float16)u0[j];
                hv[4+j] = (_Float16)u1[j];
                yv[j]   = (_Float16)fmaxf(0.f, u0[j]*s8[j]   + bb8[j]);
                yv[4+j] = (_Float16)fmaxf(0.f, u1[j]*s8[4+j] + bb8[4+j]);
            }
            *(half8*)(outH + gbase + e) = hv;
            *(half8*)(y2   + gbase + e) = yv;
        }
    } else {
        #pragma unroll
        for (int jj = 0; jj < 16; ++jj) {
            int e = (jj*256 + t) << 2;
            *(floatx4*)(outF + gbase + e) = *(const floatx4*)(sF + e);
        }
    }
}

// ---------------------------------------------------------------------------
// Sobel + K=5 diffusion + relu(bn_o). One block per (b,h) row, 1024 thr.
// R7 rewrite:
//  * ownership (w, 8ch)/thread: t -> w=t>>3, c0=(t&7)*8. Inner +-1 channel
//    shifts become register renaming; only 2 shfls/iter (was 4).
//  * 6-FMA update: cR=P+Q, cL=P-Q, cU=R+Q, cD=R-Q precomputed once
//    (was 11 ops/elem). Needs >64 VGPR -> __launch_bounds__(1024) (128 cap,
//    1 block/CU; measured occupancy at 2 blocks was only 40% anyway).
//  * LDS row stride 66 floats: unpadded [w][64] with 32B/lane b128 access
//    uses only banks {0,8,16,24} (2x); stride 66 gives 8 accesses/bank (min).
//  * all 5 global loads prefetched at block start (latency under Sobel).
//  * rcp via __builtin_amdgcn_rcpf (denoms >= 1; rel err 2^-22).
// ---------------------------------------------------------------------------
__global__ __launch_bounds__(1024)
void diffuse(const _Float16* __restrict__ f, const float* __restrict__ g,
             float* __restrict__ out,
             const float* __restrict__ bog, const float* __restrict__ bob,
             const float* __restrict__ bom, const float* __restrict__ bov)
{
    __shared__ float B0[128*LSTR], B1[128*LSTR];   // 2 x 33792 B
    const int t = threadIdx.x;
    const int rowb = ((blockIdx.x & 7) << 8) | (blockIdx.x >> 3);  // XCD swizzle
    const int b = rowb >> 7, i = rowb & 127;
    const int im = (i == 0)    ? 1    : i - 1;     // reflect
    const int ip = (i == HH-1) ? HH-2 : i + 1;
    const _Float16* fb = f + (size_t)b * (HH*ROW);
    const int e0 = t << 3;                         // elem offset in row (t*8)
    const int w  = t >> 3;
    const int c0 = (t & 7) << 3;
    const int lo = w*LSTR + c0;                    // own LDS offset (floats)
    const int lane = t & 63;
    const int srcm = (lane & 56) | ((lane - 1) & 7);   // c-ring lane-1
    const int srcp = (lane & 56) | ((lane + 1) & 7);   // c-ring lane+1

    // ---- prefetch ALL globals (latency hides under Sobel/coeff compute)
    half8 vm = *(const half8*)(fb + (size_t)im*ROW + e0);
    half8 vp = *(const half8*)(fb + (size_t)ip*ROW + e0);
    half8 v0 = *(const half8*)(fb + (size_t)i *ROW + e0);
    const float* grow = g + (size_t)rowb * ROW;
    floatx4 g0 = *(const floatx4*)(grow + e0);
    floatx4 g1 = *(const floatx4*)(grow + e0 + 4);

    // ---- stage f[i-1]->B0, f[i+1]->B1 (keep f32 copies in regs)
    float a0f[8], b0f[8];
    #pragma unroll
    for (int j = 0; j < 8; ++j) { a0f[j] = (float)vm[j]; b0f[j] = (float)vp[j]; }
    {
        floatx4 u0 = {a0f[0],a0f[1],a0f[2],a0f[3]}, u1 = {a0f[4],a0f[5],a0f[6],a0f[7]};
        floatx4 p0 = {b0f[0],b0f[1],b0f[2],b0f[3]}, p1 = {b0f[4],b0f[5],b0f[6],b0f[7]};
        *(floatx4*)(B0 + lo) = u0;  *(floatx4*)(B0 + lo + 4) = u1;
        *(floatx4*)(B1 + lo) = p0;  *(floatx4*)(B1 + lo + 4) = p1;
    }
    __syncthreads();

    // ---- Sobel partials from rows i+-1 (REFLECT in W); own col from regs
    const int wm = (w == 0)    ? 1      : w - 1;
    const int wp = (w == WW-1) ? WW - 2 : w + 1;
    float Bx[8], dxp[8];
    {
        float am[8], ap[8], bm[8], bp[8];
        floatx4 u0, u1;
        u0 = *(const floatx4*)(B0 + wm*LSTR + c0); u1 = *(const floatx4*)(B0 + wm*LSTR + c0 + 4);
        #pragma unroll
        for (int j = 0; j < 4; ++j) { am[j] = u0[j]; am[4+j] = u1[j]; }
        u0 = *(const floatx4*)(B0 + wp*LSTR + c0); u1 = *(const floatx4*)(B0 + wp*LSTR + c0 + 4);
        #pragma unroll
        for (int j = 0; j < 4; ++j) { ap[j] = u0[j]; ap[4+j] = u1[j]; }
        u0 = *(const floatx4*)(B1 + wm*LSTR + c0); u1 = *(const floatx4*)(B1 + wm*LSTR + c0 + 4);
        #pragma unroll
        for (int j = 0; j < 4; ++j) { bm[j] = u0[j]; bm[4+j] = u1[j]; }
        u0 = *(const floatx4*)(B1 + wp*LSTR + c0); u1 = *(const floatx4*)(B1 + wp*LSTR + c0 + 4);
        #pragma unroll
        for (int j = 0; j < 4; ++j) { bp[j] = u0[j]; bp[4+j] = u1[j]; }
        #pragma unroll
        for (int j = 0; j < 8; ++j) {
            float dy = (bm[j] + 2.f*b0f[j] + bp[j]) - (am[j] + 2.f*a0f[j] + ap[j]);
            Bx[j]  = 0.2f * __builtin_amdgcn_rcpf(dy*dy*0.25f + 1.f);   // Dx*DT
            dxp[j] = (ap[j] - am[j]) + (bp[j] - bm[j]);
        }
    }
    __syncthreads();

    // ---- stage f[i]->B0 (= h_0), g->B1
    float fvr[8], gfv[8];
    #pragma unroll
    for (int j = 0; j < 8; ++j) fvr[j] = (float)v0[j];
    #pragma unroll
    for (int j = 0; j < 4; ++j) { gfv[j] = g0[j]; gfv[4+j] = g1[j]; }
    {
        floatx4 u0 = {fvr[0],fvr[1],fvr[2],fvr[3]}, u1 = {fvr[4],fvr[5],fvr[6],fvr[7]};
        *(floatx4*)(B0 + lo) = u0;  *(floatx4*)(B0 + lo + 4) = u1;
        *(floatx4*)(B1 + lo) = g0;  *(floatx4*)(B1 + lo + 4) = g1;
    }
    __syncthreads();

    // ---- coefficients (6-FMA form); cyclic W offsets reused by the loop
    const int owl = ((w + WW - 1) & (WW - 1))*LSTR + c0;
    const int owr = ((w + 1) & (WW - 1))*LSTR + c0;
    float cH0[8], cEE[8], cR[8], cL[8], cU[8], cD[8], cF[8], h[8], h0v[8];
    {
        float fm[8], fp[8], gl[8], gr[8];
        floatx4 u0, u1;
        u0 = *(const floatx4*)(B0 + wm*LSTR + c0); u1 = *(const floatx4*)(B0 + wm*LSTR + c0 + 4);
        #pragma unroll
        for (int j = 0; j < 4; ++j) { fm[j] = u0[j]; fm[4+j] = u1[j]; }
        u0 = *(const floatx4*)(B0 + wp*LSTR + c0); u1 = *(const floatx4*)(B0 + wp*LSTR + c0 + 4);
        #pragma unroll
        for (int j = 0; j < 4; ++j) { fp[j] = u0[j]; fp[4+j] = u1[j]; }
        u0 = *(const floatx4*)(B1 + owl);          u1 = *(const floatx4*)(B1 + owl + 4);
        #pragma unroll
        for (int j = 0; j < 4; ++j) { gl[j] = u0[j]; gl[4+j] = u1[j]; }
        u0 = *(const floatx4*)(B1 + owr);          u1 = *(const floatx4*)(B1 + owr + 4);
        #pragma unroll
        for (int j = 0; j < 4; ++j) { gr[j] = u0[j]; gr[4+j] = u1[j]; }
        float gdm = __shfl(gfv[7], srcm, 64);      // g[c0-1] (cyclic over 64)
        float gup = __shfl(gfv[0], srcp, 64);      // g[c0+8]
        float gd[8], gu[8];
        gd[0] = gdm;
        #pragma unroll
        for (int j = 1; j < 8; ++j) gd[j] = gfv[j-1];
        #pragma unroll
        for (int j = 0; j < 7; ++j) gu[j] = gfv[j+1];
        gu[7] = gup;
        #pragma unroll
        for (int j = 0; j < 8; ++j) {
            float dx = dxp[j] + 2.f*(fp[j] - fm[j]);
            float By = 0.2f * __builtin_amdgcn_rcpf(dx*dx*0.25f + 1.f);  // Dy*DT
            float E  = ((gl[j] - gr[j]) + (gd[j] - gu[j])) * 0.1f;       // (ux+vy)*DT
            float Q  = gfv[j] * 0.2f;                                    // g*DT (pre-Dd)
            float Dd = __builtin_amdgcn_rcpf(1.f + 2.f*Bx[j] + 2.f*By);
            float P  = 2.f*Bx[j]*Dd;
            float R  = 2.f*By*Dd;
            Q *= Dd;
            cH0[j] = 2.f*Dd - 1.f;        // == Dd*(1-2Bx-2By)
            cEE[j] = -2.f*E*Dd;
            cR[j] = P + Q;  cL[j] = P - Q;
            cU[j] = R + Q;  cD[j] = R - Q;
            cF[j] = 0.4f*Dd*fvr[j];       // Dd * 2*DT*f
            h[j] = fvr[j];  h0v[j] = fvr[j];
        }
    }
    __syncthreads();                      // g reads done before loop writes B1

    // ---- K=5 diffusion, h in regs, neighbors via LDS ping-pong B0->B1->...
    float* cur = B0;
    float* oth = B1;
    #pragma unroll
    for (int it = 0; it < 5; ++it) {
        float hl[8], hr[8], hn[8];
        floatx4 u0, u1;
        u0 = *(const floatx4*)(cur + owl); u1 = *(const floatx4*)(cur + owl + 4);
        #pragma unroll
        for (int j = 0; j < 4; ++j) { hl[j] = u0[j]; hl[4+j] = u1[j]; }
        u0 = *(const floatx4*)(cur + owr); u1 = *(const floatx4*)(cur + owr + 4);
        #pragma unroll
        for (int j = 0; j < 4; ++j) { hr[j] = u0[j]; hr[4+j] = u1[j]; }
        float hdm = __shfl(h[7], srcm, 64);
        float hup = __shfl(h[0], srcp, 64);
        float hd[8], hu[8];
        hd[0] = hdm;
        #pragma unroll
        for (int j = 1; j < 8; ++j) hd[j] = h[j-1];
        #pragma unroll
        for (int j = 0; j < 7; ++j) hu[j] = h[j+1];
        hu[7] = hup;
        #pragma unroll
        for (int j = 0; j < 8; ++j) {
            float a = fmaf(cH0[j], h0v[j], cF[j]);
            a = fmaf(cEE[j], h[j],  a);
            a = fmaf(cR[j],  hr[j], a);
            a = fmaf(cL[j],  hl[j], a);
            a = fmaf(cU[j],  hu[j], a);
            a = fmaf(cD[j],  hd[j], a);
            hn[j] = a;
        }
        floatx4 w0 = {hn[0],hn[1],hn[2],hn[3]}, w1 = {hn[4],hn[5],hn[6],hn[7]};
        *(floatx4*)(oth + lo) = w0;  *(floatx4*)(oth + lo + 4) = w1;
        #pragma unroll
        for (int j = 0; j < 8; ++j) { h0v[j] = h[j]; h[j] = hn[j]; }
        __syncthreads();
        float* tmp = cur; cur = oth; oth = tmp;
    }

    // ---- epilogue: relu(bn_o(h)) from registers, float4 stores
    float s8[8], bi8[8];
    {
        floatx4 gg0 = *(const floatx4*)(bog + c0), gg1 = *(const floatx4*)(bog + c0 + 4);
        floatx4 vv0 = *(const floatx4*)(bov + c0), vv1 = *(const floatx4*)(bov + c0 + 4);
        floatx4 bb0 = *(const floatx4*)(bob + c0), bb1 = *(const floatx4*)(bob + c0 + 4);
        floatx4 mm0 = *(const floatx4*)(bom + c0), mm1 = *(const floatx4*)(bom + c0 + 4);
        #pragma unroll
        for (int j = 0; j < 4; ++j) {
            s8[j]   = gg0[j] * rsqrtf(vv0[j] + 1e-3f);
            s8[4+j] = gg1[j] * rsqrtf(vv1[j] + 1e-3f);
            bi8[j]   = bb0[j] - mm0[j]*s8[j];
            bi8[4+j] = bb1[j] - mm1[j]*s8[4+j];
        }
    }
    float* op = out + (size_t)rowb * ROW + e0;
    floatx4 r0, r1;
    #pragma unroll
    for (int j = 0; j < 4; ++j) {
        r0[j] = fmaxf(0.f, fmaf(h[j],   s8[j],   bi8[j]));
        r1[j] = fmaxf(0.f, fmaf(h[4+j], s8[4+j], bi8[4+j]));
    }
    *(floatx4*)(op)     = r0;
    *(floatx4*)(op + 4) = r1;
}

// ---------------------------------------------------------------------------
extern "C" void kernel_launch(void* const* d_in, const int* in_sizes, int n_in,
                              void* d_out, int out_size, void* d_ws, size_t ws_size,
                              hipStream_t stream)
{
    const float* x    = (const float*)d_in[0];
    const float* f_w  = (const float*)d_in[1];
    const float* g_w  = (const float*)d_in[2];
    const float* bnf_g = (const float*)d_in[3];
    const float* bnf_b = (const float*)d_in[4];
    const float* bnf_m = (const float*)d_in[5];
    const float* bnf_v = (const float*)d_in[6];
    const float* bng_g = (const float*)d_in[7];
    const float* bng_b = (const float*)d_in[8];
    const float* bng_m = (const float*)d_in[9];
    const float* bng_v = (const float*)d_in[10];
    const float* bno_g = (const float*)d_in[11];
    const float* bno_b = (const float*)d_in[12];
    const float* bno_m = (const float*)d_in[13];
    const float* bno_v = (const float*)d_in[14];

    float* out = (float*)d_out;
    const size_t N = (size_t)16 * HH * WW * CC;   // 16,777,216
    _Float16* y2   = (_Float16*)d_ws;             // N halfs (32 MB)
    _Float16* fbuf = y2 + N;                      // N halfs
    _Float16* W2f  = y2 + 2*N;                    // 36864 halfs
    _Float16* W2g  = W2f + 36864;

    repack_w<<<288, 256, 0, stream>>>(f_w, g_w, W2f, W2g);
    // conv1: stage relu(bn_f(x)) inline; write f16 f + fused y2=relu(bn_g(f))
    conv_mfma<1,1><<<1024, 256, 0, stream>>>(x, W2f, fbuf, nullptr, y2,
                                             bnf_g, bnf_b, bnf_m, bnf_v,
                                             bng_g, bng_b, bng_m, bng_v);
    // conv2: plain f16 staging from y2; write fp32 g to output slot 1
    conv_mfma<0,0><<<1024, 256, 0, stream>>>(y2, W2g, nullptr, out + N, nullptr,
                                             nullptr, nullptr, nullptr, nullptr,
                                             nullptr, nullptr, nullptr, nullptr);
    // diffusion + bn_o + relu -> output slot 0
    diffuse<<<2048, 1024, 0, stream>>>(fbuf, out + N, out, bno_g, bno_b, bno_m, bno_v);
}

// Round 3
// 323.668 us; speedup vs baseline: 1.2819x; 1.2819x over previous
//
#include <hip/hip_runtime.h>

#define HH 128
#define WW 128
#define CC 64
#define ROW (WW*CC)          // 8192 elements per (b,h) row
#define PADW 72              // f16 elems per pixel slot in conv LDS (byte stride 144 = 16*9)

typedef _Float16 half8 __attribute__((ext_vector_type(8)));
typedef _Float16 half4v __attribute__((ext_vector_type(4)));
typedef float floatx4 __attribute__((ext_vector_type(4)));

__device__ inline floatx4 rcp4(floatx4 v)
{
    floatx4 r;
    r[0] = __builtin_amdgcn_rcpf(v[0]);
    r[1] = __builtin_amdgcn_rcpf(v[1]);
    r[2] = __builtin_amdgcn_rcpf(v[2]);
    r[3] = __builtin_amdgcn_rcpf(v[3]);
    return r;
}

// ---------------------------------------------------------------------------
// Repack HWIO fp32 weights [3][3][64][64] -> f16 B-frag layout:
// W2[(step*4+q)*512 + o*8 + j] = W[tap][kc*32+q*8+j][o], step = tap*2+kc
// ---------------------------------------------------------------------------
__global__ __launch_bounds__(256)
void repack_w(const float* __restrict__ wf, const float* __restrict__ wg,
              _Float16* __restrict__ W2f, _Float16* __restrict__ W2g)
{
    int idx = blockIdx.x * 256 + threadIdx.x;      // 0..73727
    int sel = idx >= 36864;
    int id  = sel ? idx - 36864 : idx;             // (t*64 + c)*64 + o
    const float* src = sel ? wg : wf;
    _Float16* dst = sel ? W2g : W2f;
    int t = id >> 12, c = (id >> 6) & 63, o = id & 63;
    int kc = c >> 5, q = (c >> 3) & 3, j = c & 7;
    int pos = ((((t*2 + kc)*4 + q)*64 + o) << 3) + j;
    dst[pos] = (_Float16)src[id];
}

// ---------------------------------------------------------------------------
// Implicit-GEMM 3x3 SAME conv via f16 MFMA.  (unchanged - verified at 344us)
// Block = 2 output rows (b, i0..i0+1). LDS: 4 input rows, 130 px slots, PADW.
// Wave = 64 px x 64 couts: acc[4][4], 16 MFMAs per 4 B-frag loads.
// Epilogue restages fp32 acc through LDS -> lane-contiguous vector stores.
// XCD-bijective swizzle (1024 = 8 x 128) for halo-row L2 locality.
// ---------------------------------------------------------------------------
template<int BNIN, int EPI>
__global__ __launch_bounds__(256, 2)
void conv_mfma(const void* __restrict__ srcv, const _Float16* __restrict__ W2,
               _Float16* __restrict__ outH, float* __restrict__ outF,
               _Float16* __restrict__ y2,
               const float* __restrict__ ig, const float* __restrict__ ib,
               const float* __restrict__ imu, const float* __restrict__ iva,
               const float* __restrict__ og, const float* __restrict__ ob,
               const float* __restrict__ om, const float* __restrict__ ov)
{
    __shared__ __align__(16) _Float16 sIn[4*130*PADW];   // 74880 B -> 2 blocks/CU
    const int t = threadIdx.x;
    const int blk = ((blockIdx.x & 7) << 7) | (blockIdx.x >> 3);  // XCD swizzle
    const int b = blk >> 6, i0 = (blk & 63) * 2;

    // per-thread BN constants for staging (c8 = (t&7)*8 is k-invariant)
    const int c8 = (t & 7) << 3;
    float scv[8], biv[8];
    if (BNIN) {
        #pragma unroll
        for (int j = 0; j < 8; ++j) {
            float s = ig[c8+j] * rsqrtf(iva[c8+j] + 1e-3f);
            scv[j] = s; biv[j] = ib[c8+j] - imu[c8+j]*s;
        }
    }

    // stage 4 input rows (i0-1 .. i0+2)
    for (int r = 0; r < 4; ++r) {
        int iy = i0 - 1 + r;
        bool inb = (iy >= 0) && (iy < HH);
        #pragma unroll
        for (int k = 0; k < 4; ++k) {
            int idx = t + (k << 8);
            int px = idx >> 3;
            half8 v = {0,0,0,0,0,0,0,0};
            if (inb) {
                if (BNIN) {
                    const float* gp = (const float*)srcv
                        + ((size_t)(b*HH + iy))*ROW + px*CC + c8;
                    float4 u0 = *(const float4*)gp;
                    float4 u1 = *(const float4*)(gp + 4);
                    v[0] = (_Float16)fmaxf(0.f, u0.x*scv[0] + biv[0]);
                    v[1] = (_Float16)fmaxf(0.f, u0.y*scv[1] + biv[1]);
                    v[2] = (_Float16)fmaxf(0.f, u0.z*scv[2] + biv[2]);
                    v[3] = (_Float16)fmaxf(0.f, u0.w*scv[3] + biv[3]);
                    v[4] = (_Float16)fmaxf(0.f, u1.x*scv[4] + biv[4]);
                    v[5] = (_Float16)fmaxf(0.f, u1.y*scv[5] + biv[5]);
                    v[6] = (_Float16)fmaxf(0.f, u1.z*scv[6] + biv[6]);
                    v[7] = (_Float16)fmaxf(0.f, u1.w*scv[7] + biv[7]);
                } else {
                    v = *(const half8*)((const _Float16*)srcv
                        + ((size_t)(b*HH + iy))*ROW + px*CC + c8);
                }
            }
            *(half8*)(sIn + (r*130 + px + 1)*PADW + c8) = v;
        }
    }
    // zero edge pixel slots (0 and 129) x 4 rows
    if (t < 128) {
        int rr = t >> 5, s = (t >> 4) & 1, c4 = (t & 15) << 2;
        int slot = s ? 129 : 0;
        half4v z = {0,0,0,0};
        *(half4v*)(sIn + (rr*130 + slot)*PADW + c4) = z;
    }
    __syncthreads();

    const int wv = t >> 6, lane = t & 63;
    const int lm = lane & 15, quad = lane >> 4;
    const int r  = wv >> 1;                        // local output row 0/1
    const int px0 = (wv & 1) * 64;
    floatx4 z4 = {0.f,0.f,0.f,0.f};
    floatx4 acc[4][4];
    #pragma unroll
    for (int ms = 0; ms < 4; ++ms)
        #pragma unroll
        for (int nt = 0; nt < 4; ++nt) acc[ms][nt] = z4;

    #pragma unroll
    for (int tap = 0; tap < 9; ++tap) {
        const int di = tap / 3, dj = tap % 3;
        #pragma unroll
        for (int kc = 0; kc < 2; ++kc) {
            const _Float16* ab = sIn + ((r + di)*130 + px0 + lm + dj)*PADW
                               + kc*32 + quad*8;
            half8 a0 = *(const half8*)(ab);
            half8 a1 = *(const half8*)(ab + 16*PADW);
            half8 a2 = *(const half8*)(ab + 32*PADW);
            half8 a3 = *(const half8*)(ab + 48*PADW);
            const _Float16* wb = W2 + (((tap*2 + kc)*4 + quad) << 9) + (lm << 3);
            half8 b0 = *(const half8*)(wb);
            half8 b1 = *(const half8*)(wb + 128);
            half8 b2 = *(const half8*)(wb + 256);
            half8 b3 = *(const half8*)(wb + 384);
            acc[0][0] = __builtin_amdgcn_mfma_f32_16x16x32_f16(a0, b0, acc[0][0], 0,0,0);
            acc[1][0] = __builtin_amdgcn_mfma_f32_16x16x32_f16(a1, b0, acc[1][0], 0,0,0);
            acc[2][0] = __builtin_amdgcn_mfma_f32_16x16x32_f16(a2, b0, acc[2][0], 0,0,0);
            acc[3][0] = __builtin_amdgcn_mfma_f32_16x16x32_f16(a3, b0, acc[3][0], 0,0,0);
            acc[0][1] = __builtin_amdgcn_mfma_f32_16x16x32_f16(a0, b1, acc[0][1], 0,0,0);
            acc[1][1] = __builtin_amdgcn_mfma_f32_16x16x32_f16(a1, b1, acc[1][1], 0,0,0);
            acc[2][1] = __builtin_amdgcn_mfma_f32_16x16x32_f16(a2, b1, acc[2][1], 0,0,0);
            acc[3][1] = __builtin_amdgcn_mfma_f32_16x16x32_f16(a3, b1, acc[3][1], 0,0,0);
            acc[0][2] = __builtin_amdgcn_mfma_f32_16x16x32_f16(a0, b2, acc[0][2], 0,0,0);
            acc[1][2] = __builtin_amdgcn_mfma_f32_16x16x32_f16(a1, b2, acc[1][2], 0,0,0);
            acc[2][2] = __builtin_amdgcn_mfma_f32_16x16x32_f16(a2, b2, acc[2][2], 0,0,0);
            acc[3][2] = __builtin_amdgcn_mfma_f32_16x16x32_f16(a3, b2, acc[3][2], 0,0,0);
            acc[0][3] = __builtin_amdgcn_mfma_f32_16x16x32_f16(a0, b3, acc[0][3], 0,0,0);
            acc[1][3] = __builtin_amdgcn_mfma_f32_16x16x32_f16(a1, b3, acc[1][3], 0,0,0);
            acc[2][3] = __builtin_amdgcn_mfma_f32_16x16x32_f16(a2, b3, acc[2][3], 0,0,0);
            acc[3][3] = __builtin_amdgcn_mfma_f32_16x16x32_f16(a3, b3, acc[3][3], 0,0,0);
        }
    }

    // ---- epilogue: restage fp32 acc -> LDS [256 px][64 c], then vector copy-out
    __syncthreads();                               // all A-frag reads done
    float* sF = (float*)sIn;                       // 64 KB of the 74880 B
    #pragma unroll
    for (int nt = 0; nt < 4; ++nt) {
        int c = nt*16 + lm;
        #pragma unroll
        for (int ms = 0; ms < 4; ++ms) {
            int pix = r*128 + px0 + ms*16 + quad*4;
            floatx4 v = acc[ms][nt];
            #pragma unroll
            for (int rv = 0; rv < 4; ++rv)
                sF[(pix + rv)*64 + c] = v[rv];
        }
    }
    __syncthreads();

    const size_t gbase = ((size_t)(b*HH + i0)) * ROW;   // 2 contiguous rows
    if (EPI) {
        const int c8o = (t & 7) << 3;             // elem%64 of (jj*256+t)*8
        float s8[8], bb8[8];
        #pragma unroll
        for (int j = 0; j < 8; ++j) {
            float ss = og[c8o+j] * rsqrtf(ov[c8o+j] + 1e-3f);
            s8[j] = ss; bb8[j] = ob[c8o+j] - om[c8o+j]*ss;
        }
        #pragma unroll
        for (int jj = 0; jj < 8; ++jj) {
            int e = (jj*256 + t) << 3;            // 0..16383, lane-contiguous
            floatx4 u0 = *(const floatx4*)(sF + e);
            floatx4 u1 = *(const floatx4*)(sF + e + 4);
            half8 hv, yv;
            #pragma unroll
            for (int j = 0; j < 4; ++j) {
                hv[j]   = (_Float16)u0[j];
                hv[4+j] = (_Float16)u1[j];
                yv[j]   = (_Float16)fmaxf(0.f, u0[j]*s8[j]   + bb8[j]);
                yv[4+j] = (_Float16)fmaxf(0.f, u1[j]*s8[4+j] + bb8[4+j]);
            }
            *(half8*)(outH + gbase + e) = hv;
            *(half8*)(y2   + gbase + e) = yv;
        }
    } else {
        #pragma unroll
        for (int jj = 0; jj < 16; ++jj) {
            int e = (jj*256 + t) << 2;
            *(floatx4*)(outF + gbase + e) = *(const floatx4*)(sF + e);
        }
    }
}

// ---------------------------------------------------------------------------
// Sobel + K=5 diffusion + relu(bn_o). One block per (b,h) row, 1024 thr.
// R8: back to the R6 memory structure (proven 87us, 0 bank conflicts):
//   [w][64] LDS stride, w0=t>>4, c0=(t&15)*4, 2 k-slots/thread, C via shfl.
// Register-only deltas vs R6 (layout untouched):
//   * edge-folded coefficients cR=P+Q, cL=P-Q, cU=R+Q precomputed (same
//     8 float4/slot state as R6); cD = cU-cR+cL recomputed per iter.
//     K-loop: 6 FMA + 2 ops (was ~11 ops).
//   * __builtin_amdgcn_rcpf for Bx/By/Dd (denoms >= 1; numerics verified R7).
//   * last iteration skips the LDS write + barrier (no reader).
// ---------------------------------------------------------------------------
__global__ __launch_bounds__(1024, 2)
void diffuse(const _Float16* __restrict__ f, const float* __restrict__ g,
             float* __restrict__ out,
             const float* __restrict__ bog, const float* __restrict__ bob,
             const float* __restrict__ bom, const float* __restrict__ bov)
{
    __shared__ float B0[ROW], B1[ROW];     // 2 x 32 KB
    const int t = threadIdx.x;
    const int rowb = ((blockIdx.x & 7) << 8) | (blockIdx.x >> 3);  // XCD swizzle
    const int b = rowb >> 7, i = rowb & 127;
    const int im = (i == 0)    ? 1    : i - 1;   // reflect
    const int ip = (i == HH-1) ? HH-2 : i + 1;
    const _Float16* fb  = f + (size_t)b * (HH*ROW);
    const _Float16* frm = fb + (size_t)im * ROW;
    const _Float16* fr0 = fb + (size_t)i  * ROW;
    const _Float16* frp = fb + (size_t)ip * ROW;
    const float* grow = g + (size_t)rowb * ROW;

    const int lane = t & 63;
    const int srcm = (lane & 48) | ((lane - 1) & 15);   // c-group lane-1 (cyclic)
    const int srcp = (lane & 48) | ((lane + 1) & 15);   // c-group lane+1 (cyclic)
    const int w0 = t >> 4, c0 = (t & 15) << 2;
    const int qch[2] = { t*4, t*4 + 4096 };
    const int wch[2] = { w0, w0 + 64 };

    // ---- stage f[i-1]->B0, f[i+1]->B1
    #pragma unroll
    for (int k = 0; k < 2; ++k) {
        half4v vm = *(const half4v*)(frm + qch[k]);
        half4v vp = *(const half4v*)(frp + qch[k]);
        floatx4 a = { (float)vm[0], (float)vm[1], (float)vm[2], (float)vm[3] };
        floatx4 p = { (float)vp[0], (float)vp[1], (float)vp[2], (float)vp[3] };
        *(floatx4*)(B0 + qch[k]) = a;
        *(floatx4*)(B1 + qch[k]) = p;
    }
    __syncthreads();

    // ---- Sobel partials from rows i+-1 (REFLECT in W)
    floatx4 Bx4[2], dxp4[2];
    #pragma unroll
    for (int k = 0; k < 2; ++k) {
        int w = wch[k];
        int wm = (w == 0)    ? 1      : w - 1;
        int wp = (w == WW-1) ? WW - 2 : w + 1;
        floatx4 am = *(const floatx4*)(B0 + wm*CC + c0);
        floatx4 a0 = *(const floatx4*)(B0 + w *CC + c0);
        floatx4 ap = *(const floatx4*)(B0 + wp*CC + c0);
        floatx4 bm = *(const floatx4*)(B1 + wm*CC + c0);
        floatx4 b0 = *(const floatx4*)(B1 + w *CC + c0);
        floatx4 bp = *(const floatx4*)(B1 + wp*CC + c0);
        floatx4 dy = (bm + 2.f*b0 + bp) - (am + 2.f*a0 + ap);
        Bx4[k]  = 0.2f * rcp4(dy*dy*0.25f + 1.f);  // Dx*DT
        dxp4[k] = (ap - am) + (bp - bm);
    }
    __syncthreads();

    // ---- stage f[i]->B0 (= h_0), g->B1
    #pragma unroll
    for (int k = 0; k < 2; ++k) {
        half4v v0 = *(const half4v*)(fr0 + qch[k]);
        floatx4 fv = { (float)v0[0], (float)v0[1], (float)v0[2], (float)v0[3] };
        *(floatx4*)(B0 + qch[k]) = fv;
        *(floatx4*)(B1 + qch[k]) = *(const floatx4*)(grow + qch[k]);
    }
    __syncthreads();

    // ---- coefficients (edge-folded form; same state count as R6)
    floatx4 cR4[2], cL4[2], cU4[2], cH0[2], cEE[2], cF[2], h4[2], h04[2];
    #pragma unroll
    for (int k = 0; k < 2; ++k) {
        int w = wch[k];
        int wm = (w == 0)    ? 1      : w - 1;     // reflect (sobel dx)
        int wp = (w == WW-1) ? WW - 2 : w + 1;
        int wl = (w + WW - 1) & (WW - 1);          // cyclic (rolls)
        int wr = (w + 1) & (WW - 1);
        floatx4 fm = *(const floatx4*)(B0 + wm*CC + c0);
        floatx4 fv = *(const floatx4*)(B0 + w *CC + c0);
        floatx4 fp = *(const floatx4*)(B0 + wp*CC + c0);
        floatx4 dx = dxp4[k] + 2.f*(fp - fm);
        floatx4 By = 0.2f * rcp4(dx*dx*0.25f + 1.f);    // Dy*DT
        floatx4 Bx = Bx4[k];
        floatx4 gv = *(const floatx4*)(B1 + w *CC + c0);
        floatx4 gl = *(const floatx4*)(B1 + wl*CC + c0);
        floatx4 gr = *(const floatx4*)(B1 + wr*CC + c0);
        float gdm = __shfl(gv[3], srcm, 64);       // g[c0-1] from lane-1
        float gup = __shfl(gv[0], srcp, 64);       // g[c0+4] from lane+1
        floatx4 gd = { gdm, gv[0], gv[1], gv[2] };
        floatx4 gu = { gv[1], gv[2], gv[3], gup };
        floatx4 E  = ((gl - gr) + (gd - gu)) * 0.1f;     // (ux+vy)*DT
        floatx4 Dd = rcp4(1.f + 2.f*Bx + 2.f*By);
        floatx4 P  = 2.f * Bx * Dd;
        floatx4 R  = 2.f * By * Dd;
        floatx4 Q  = (gv * 0.2f) * Dd;             // g*DT*Dd
        cR4[k] = P + Q;
        cL4[k] = P - Q;
        cU4[k] = R + Q;
        cH0[k] = 2.f*Dd - 1.f;            // == Dd*(1-2Bx-2By)
        cEE[k] = -2.f * E * Dd;
        cF[k]  = 0.4f * Dd * fv;          // Dd * 2*DT*f
        h4[k] = fv; h04[k] = fv;
    }
    __syncthreads();                      // g reads done before loop writes B1

    // loop-invariant LDS offsets (W-direction only; C via shfl)
    int oWl[2], oWr[2];
    #pragma unroll
    for (int k = 0; k < 2; ++k) {
        int w = wch[k];
        oWl[k] = ((w + WW - 1) & (WW - 1))*CC + c0;
        oWr[k] = ((w + 1) & (WW - 1))*CC + c0;
    }

    // ---- K=5 diffusion, h ping-pong B0 -> B1 -> B0 ... (last iter reg-only)
    float* cur = B0;
    float* oth = B1;
    for (int it = 0; it < 5; ++it) {
        #pragma unroll
        for (int k = 0; k < 2; ++k) {
            floatx4 hl = *(const floatx4*)(cur + oWl[k]);
            floatx4 hr = *(const floatx4*)(cur + oWr[k]);
            floatx4 hv = h4[k];
            float hdm = __shfl(hv[3], srcm, 64);
            float hup = __shfl(hv[0], srcp, 64);
            floatx4 hd = { hdm, hv[0], hv[1], hv[2] };
            floatx4 hu = { hv[1], hv[2], hv[3], hup };
            floatx4 cD = (cU4[k] - cR4[k]) + cL4[k];     // R - Q
            floatx4 hn = cH0[k]*h04[k] + cEE[k]*hv
                       + cR4[k]*hr + cL4[k]*hl
                       + cU4[k]*hu + cD*hd + cF[k];
            if (it < 4)
                *(floatx4*)(oth + qch[k]) = hn;
            h04[k] = hv; h4[k] = hn;
        }
        if (it < 4) {
            __syncthreads();
            float* tmp = cur; cur = oth; oth = tmp;
        }
    }

    // ---- epilogue: relu(bn_o(h)) from registers, float4 stores
    floatx4 gg = *(const floatx4*)(bog + c0);
    floatx4 vv = *(const floatx4*)(bov + c0);
    floatx4 bb = *(const floatx4*)(bob + c0);
    floatx4 mm = *(const floatx4*)(bom + c0);
    floatx4 s4, bi4;
    #pragma unroll
    for (int j = 0; j < 4; ++j) s4[j] = gg[j] * rsqrtf(vv[j] + 1e-3f);
    bi4 = bb - mm*s4;
    float* op = out + (size_t)rowb * ROW;
    #pragma unroll
    for (int k = 0; k < 2; ++k) {
        floatx4 rr = h4[k]*s4 + bi4;
        #pragma unroll
        for (int j = 0; j < 4; ++j) rr[j] = fmaxf(0.f, rr[j]);
        *(floatx4*)(op + qch[k]) = rr;
    }
}

// ---------------------------------------------------------------------------
extern "C" void kernel_launch(void* const* d_in, const int* in_sizes, int n_in,
                              void* d_out, int out_size, void* d_ws, size_t ws_size,
                              hipStream_t stream)
{
    const float* x    = (const float*)d_in[0];
    const float* f_w  = (const float*)d_in[1];
    const float* g_w  = (const float*)d_in[2];
    const float* bnf_g = (const float*)d_in[3];
    const float* bnf_b = (const float*)d_in[4];
    const float* bnf_m = (const float*)d_in[5];
    const float* bnf_v = (const float*)d_in[6];
    const float* bng_g = (const float*)d_in[7];
    const float* bng_b = (const float*)d_in[8];
    const float* bng_m = (const float*)d_in[9];
    const float* bng_v = (const float*)d_in[10];
    const float* bno_g = (const float*)d_in[11];
    const float* bno_b = (const float*)d_in[12];
    const float* bno_m = (const float*)d_in[13];
    const float* bno_v = (const float*)d_in[14];

    float* out = (float*)d_out;
    const size_t N = (size_t)16 * HH * WW * CC;   // 16,777,216
    _Float16* y2   = (_Float16*)d_ws;             // N halfs (32 MB)
    _Float16* fbuf = y2 + N;                      // N halfs
    _Float16* W2f  = y2 + 2*N;                    // 36864 halfs
    _Float16* W2g  = W2f + 36864;

    repack_w<<<288, 256, 0, stream>>>(f_w, g_w, W2f, W2g);
    // conv1: stage relu(bn_f(x)) inline; write f16 f + fused y2=relu(bn_g(f))
    conv_mfma<1,1><<<1024, 256, 0, stream>>>(x, W2f, fbuf, nullptr, y2,
                                             bnf_g, bnf_b, bnf_m, bnf_v,
                                             bng_g, bng_b, bng_m, bng_v);
    // conv2: plain f16 staging from y2; write fp32 g to output slot 1
    conv_mfma<0,0><<<1024, 256, 0, stream>>>(y2, W2g, nullptr, out + N, nullptr,
                                             nullptr, nullptr, nullptr, nullptr,
                                             nullptr, nullptr, nullptr, nullptr);
    // diffusion + bn_o + relu -> output slot 0
    diffuse<<<2048, 1024, 0, stream>>>(fbuf, out + N, out, bno_g, bno_b, bno_m, bno_v);
}

// Round 4
// 321.099 us; speedup vs baseline: 1.2921x; 1.0080x over previous
//
#include <hip/hip_runtime.h>

#define HH 128
#define WW 128
#define CC 64
#define ROW (WW*CC)          // 8192 elements per (b,h) row
#define SLOTB 128            // bytes per px slot in conv LDS (64 f16, linear)
#define ROWB (130*SLOTB)     // 16640 B per staged row (130 slots)
#define FSTR 68              // conv epilogue restage stride (floats) - conflict-free

typedef _Float16 half8 __attribute__((ext_vector_type(8)));
typedef _Float16 half4v __attribute__((ext_vector_type(4)));
typedef float floatx4 __attribute__((ext_vector_type(4)));

__device__ inline floatx4 rcp4(floatx4 v)
{
    floatx4 r;
    r[0] = __builtin_amdgcn_rcpf(v[0]);
    r[1] = __builtin_amdgcn_rcpf(v[1]);
    r[2] = __builtin_amdgcn_rcpf(v[2]);
    r[3] = __builtin_amdgcn_rcpf(v[3]);
    return r;
}

// ---------------------------------------------------------------------------
// Repack HWIO fp32 weights [3][3][64][64] -> f16 B-frag layout:
// W2[(step*4+q)*512 + o*8 + j] = W[tap][kc*32+q*8+j][o], step = tap*2+kc
// ---------------------------------------------------------------------------
__global__ __launch_bounds__(256)
void repack_w(const float* __restrict__ wf, const float* __restrict__ wg,
              _Float16* __restrict__ W2f, _Float16* __restrict__ W2g)
{
    int idx = blockIdx.x * 256 + threadIdx.x;      // 0..73727
    int sel = idx >= 36864;
    int id  = sel ? idx - 36864 : idx;             // (t*64 + c)*64 + o
    const float* src = sel ? wg : wf;
    _Float16* dst = sel ? W2g : W2f;
    int t = id >> 12, c = (id >> 6) & 63, o = id & 63;
    int kc = c >> 5, q = (c >> 3) & 3, j = c & 7;
    int pos = ((((t*2 + kc)*4 + q)*64 + o) << 3) + j;
    dst[pos] = (_Float16)src[id];
}

// ---------------------------------------------------------------------------
// Implicit-GEMM 3x3 SAME conv via f16 MFMA.
// Block = 2 output rows (b, i0..i0+1). LDS: 4 input rows x 130 slots x 64 f16,
// LINEAR layout (SLOTB=128) with XOR channel-block swizzle:
//   LDS(slot, e) holds value(px=slot-1, channel = e ^ ((slot&7)<<3)).
// A-frag read XORs the same key -> channels delivered in canonical order;
// bank spread identical to the old PADW=72 scheme (minimum 8 dw/bank).
// R9:
//  * BNIN=0 (conv2): staging via __builtin_amdgcn_global_load_lds width-16
//    (fire-and-forget DMA, no VGPR round-trip). Requires y2 to be stored
//    PRE-SWIZZLED, which conv1's epilogue now does (16B stores, coalesced).
//  * BNIN=1 (conv1): ds_write staging with the XOR applied to the address.
//  * epilogue restage stride 68 floats: scattered acc writes AND vector
//    read-back both exactly 2 lanes/bank (was 4-way conflicted at stride 64).
//  * LDS 74880 -> 69632 B, still 2 blocks/CU.
// C/D: col(lane&15)=cout, row(quad*4+reg)=pixel  [m89-verified, proven R3-R8]
// ---------------------------------------------------------------------------
template<int BNIN, int EPI>
__global__ __launch_bounds__(256, 2)
void conv_mfma(const void* __restrict__ srcv, const _Float16* __restrict__ W2,
               _Float16* __restrict__ outH, float* __restrict__ outF,
               _Float16* __restrict__ y2,
               const float* __restrict__ ig, const float* __restrict__ ib,
               const float* __restrict__ imu, const float* __restrict__ iva,
               const float* __restrict__ og, const float* __restrict__ ob,
               const float* __restrict__ om, const float* __restrict__ ov)
{
    __shared__ __align__(16) char smem[69632];     // max(stage 66560, restage 69632)
    const int t = threadIdx.x;
    const int blk = ((blockIdx.x & 7) << 7) | (blockIdx.x >> 3);  // XCD swizzle
    const int b = blk >> 6, i0 = (blk & 63) * 2;

    // per-thread BN constants for staging (c8 = (t&7)*8 is k-invariant)
    const int c8 = (t & 7) << 3;
    float scv[8], biv[8];
    if (BNIN) {
        #pragma unroll
        for (int j = 0; j < 8; ++j) {
            float s = ig[c8+j] * rsqrtf(iva[c8+j] + 1e-3f);
            scv[j] = s; biv[j] = ib[c8+j] - imu[c8+j]*s;
        }
    }

    // zero edge pixel slots (0 and 129) x 4 rows: 256 thr x 4 B
    {
        int rr = t >> 6, s = (t >> 5) & 1;
        *(float*)(smem + rr*ROWB + (s ? 129*SLOTB : 0) + ((t & 31) << 2)) = 0.f;
    }

    // ---- stage 4 input rows (i0-1 .. i0+2)
    if (BNIN) {
        for (int r = 0; r < 4; ++r) {
            int iy = i0 - 1 + r;
            bool inb = (iy >= 0) && (iy < HH);
            #pragma unroll
            for (int k = 0; k < 4; ++k) {
                int idx = t + (k << 8);
                int px = idx >> 3;
                half8 v = {0,0,0,0,0,0,0,0};
                if (inb) {
                    const float* gp = (const float*)srcv
                        + ((size_t)(b*HH + iy))*ROW + px*CC + c8;
                    float4 u0 = *(const float4*)gp;
                    float4 u1 = *(const float4*)(gp + 4);
                    v[0] = (_Float16)fmaxf(0.f, u0.x*scv[0] + biv[0]);
                    v[1] = (_Float16)fmaxf(0.f, u0.y*scv[1] + biv[1]);
                    v[2] = (_Float16)fmaxf(0.f, u0.z*scv[2] + biv[2]);
                    v[3] = (_Float16)fmaxf(0.f, u0.w*scv[3] + biv[3]);
                    v[4] = (_Float16)fmaxf(0.f, u1.x*scv[4] + biv[4]);
                    v[5] = (_Float16)fmaxf(0.f, u1.y*scv[5] + biv[5]);
                    v[6] = (_Float16)fmaxf(0.f, u1.z*scv[6] + biv[6]);
                    v[7] = (_Float16)fmaxf(0.f, u1.w*scv[7] + biv[7]);
                }
                int key = ((px + 1) & 7) << 4;             // byte-granular key
                *(half8*)(smem + r*ROWB + (px + 1)*SLOTB
                          + ((((t & 7) << 4)) ^ key)) = v;
            }
        }
    } else {
        // pure-copy staging from pre-swizzled y2 via global_load_lds (16 B)
        const _Float16* src = (const _Float16*)srcv;
        #pragma unroll
        for (int r = 0; r < 4; ++r) {
            int iy = i0 - 1 + r;
            char* lb = smem + r*ROWB + SLOTB;              // interior slots 1..128
            if (iy >= 0 && iy < HH) {
                const _Float16* gp = src + (size_t)(b*HH + iy)*ROW;
                #pragma unroll
                for (int k = 0; k < 4; ++k) {
                    int eo = ((k << 8) + t) << 3;          // elem offset 0..8184
                    __builtin_amdgcn_global_load_lds(
                        (const __attribute__((address_space(1))) void*)(gp + eo),
                        (__attribute__((address_space(3))) void*)(lb + (eo << 1)),
                        16, 0, 0);
                }
            } else {
                half8 z = {0,0,0,0,0,0,0,0};
                #pragma unroll
                for (int k = 0; k < 4; ++k)
                    *(half8*)(lb + (((k << 8) + t) << 4)) = z;
            }
        }
    }
    __syncthreads();

    const int wv = t >> 6, lane = t & 63;
    const int lm = lane & 15, quad = lane >> 4;
    const int r  = wv >> 1;                        // local output row 0/1
    const int px0 = (wv & 1) * 64;
    floatx4 z4 = {0.f,0.f,0.f,0.f};
    floatx4 acc[4][4];
    #pragma unroll
    for (int ms = 0; ms < 4; ++ms)
        #pragma unroll
        for (int nt = 0; nt < 4; ++nt) acc[ms][nt] = z4;

    #pragma unroll
    for (int tap = 0; tap < 9; ++tap) {
        const int di = tap / 3, dj = tap % 3;
        const int slot = px0 + lm + dj;
        const int key  = (slot & 7) << 4;          // preserved under slot+16
        const char* abase = smem + (r + di)*ROWB + slot*SLOTB;
        #pragma unroll
        for (int kc = 0; kc < 2; ++kc) {
            const char* ab = abase + ((kc*64 + quad*16) ^ key);
            half8 a0 = *(const half8*)(ab);
            half8 a1 = *(const half8*)(ab + 16*SLOTB);
            half8 a2 = *(const half8*)(ab + 32*SLOTB);
            half8 a3 = *(const half8*)(ab + 48*SLOTB);
            const _Float16* wb = W2 + (((tap*2 + kc)*4 + quad) << 9) + (lm << 3);
            half8 b0 = *(const half8*)(wb);
            half8 b1 = *(const half8*)(wb + 128);
            half8 b2 = *(const half8*)(wb + 256);
            half8 b3 = *(const half8*)(wb + 384);
            acc[0][0] = __builtin_amdgcn_mfma_f32_16x16x32_f16(a0, b0, acc[0][0], 0,0,0);
            acc[1][0] = __builtin_amdgcn_mfma_f32_16x16x32_f16(a1, b0, acc[1][0], 0,0,0);
            acc[2][0] = __builtin_amdgcn_mfma_f32_16x16x32_f16(a2, b0, acc[2][0], 0,0,0);
            acc[3][0] = __builtin_amdgcn_mfma_f32_16x16x32_f16(a3, b0, acc[3][0], 0,0,0);
            acc[0][1] = __builtin_amdgcn_mfma_f32_16x16x32_f16(a0, b1, acc[0][1], 0,0,0);
            acc[1][1] = __builtin_amdgcn_mfma_f32_16x16x32_f16(a1, b1, acc[1][1], 0,0,0);
            acc[2][1] = __builtin_amdgcn_mfma_f32_16x16x32_f16(a2, b1, acc[2][1], 0,0,0);
            acc[3][1] = __builtin_amdgcn_mfma_f32_16x16x32_f16(a3, b1, acc[3][1], 0,0,0);
            acc[0][2] = __builtin_amdgcn_mfma_f32_16x16x32_f16(a0, b2, acc[0][2], 0,0,0);
            acc[1][2] = __builtin_amdgcn_mfma_f32_16x16x32_f16(a1, b2, acc[1][2], 0,0,0);
            acc[2][2] = __builtin_amdgcn_mfma_f32_16x16x32_f16(a2, b2, acc[2][2], 0,0,0);
            acc[3][2] = __builtin_amdgcn_mfma_f32_16x16x32_f16(a3, b2, acc[3][2], 0,0,0);
            acc[0][3] = __builtin_amdgcn_mfma_f32_16x16x32_f16(a0, b3, acc[0][3], 0,0,0);
            acc[1][3] = __builtin_amdgcn_mfma_f32_16x16x32_f16(a1, b3, acc[1][3], 0,0,0);
            acc[2][3] = __builtin_amdgcn_mfma_f32_16x16x32_f16(a2, b3, acc[2][3], 0,0,0);
            acc[3][3] = __builtin_amdgcn_mfma_f32_16x16x32_f16(a3, b3, acc[3][3], 0,0,0);
        }
    }

    // ---- epilogue: restage fp32 acc -> LDS [256 px][FSTR], vector copy-out
    __syncthreads();                               // all A-frag reads done
    float* sF = (float*)smem;
    #pragma unroll
    for (int nt = 0; nt < 4; ++nt) {
        int c = nt*16 + lm;
        #pragma unroll
        for (int ms = 0; ms < 4; ++ms) {
            int pix = r*128 + px0 + ms*16 + quad*4;
            floatx4 v = acc[ms][nt];
            #pragma unroll
            for (int rv = 0; rv < 4; ++rv)
                sF[(pix + rv)*FSTR + c] = v[rv];
        }
    }
    __syncthreads();

    const size_t gbase = ((size_t)(b*HH + i0)) * ROW;   // 2 contiguous rows
    if (EPI) {
        const int c8o = (t & 7) << 3;
        float s8[8], bb8[8];
        #pragma unroll
        for (int j = 0; j < 8; ++j) {
            float ss = og[c8o+j] * rsqrtf(ov[c8o+j] + 1e-3f);
            s8[j] = ss; bb8[j] = ob[c8o+j] - om[c8o+j]*ss;
        }
        #pragma unroll
        for (int jj = 0; jj < 8; ++jj) {
            int chunk = jj*256 + t;                // 0..2047
            int px = chunk >> 3;                   // 0..255
            const float* sp = sF + px*FSTR + c8o;
            floatx4 u0 = *(const floatx4*)(sp);
            floatx4 u1 = *(const floatx4*)(sp + 4);
            half8 hv, yv;
            #pragma unroll
            for (int j = 0; j < 4; ++j) {
                hv[j]   = (_Float16)u0[j];
                hv[4+j] = (_Float16)u1[j];
                yv[j]   = (_Float16)fmaxf(0.f, u0[j]*s8[j]   + bb8[j]);
                yv[4+j] = (_Float16)fmaxf(0.f, u1[j]*s8[4+j] + bb8[4+j]);
            }
            size_t oe = gbase + (size_t)px*64 + c8o;
            *(half8*)(outH + oe) = hv;
            // y2 stored PRE-SWIZZLED for conv2's global_load_lds staging
            int key8 = ((px + 1) & 7) << 3;
            *(half8*)(y2 + gbase + (size_t)px*64 + (c8o ^ key8)) = yv;
        }
    } else {
        #pragma unroll
        for (int jj = 0; jj < 8; ++jj) {
            int chunk = jj*256 + t;
            int px = chunk >> 3;
            const int cc = (t & 7) << 3;
            const float* sp = sF + px*FSTR + cc;
            size_t oe = gbase + (size_t)px*64 + cc;
            *(floatx4*)(outF + oe)     = *(const floatx4*)(sp);
            *(floatx4*)(outF + oe + 4) = *(const floatx4*)(sp + 4);
        }
    }
}

// ---------------------------------------------------------------------------
// Sobel + K=5 diffusion + relu(bn_o). One block per (b,h) row, 1024 thr.
// R8 structure (proven): R6 memory layout ([w][64], float4/lane, C via shfl),
// edge-folded coefficients (6 FMA + 2 ops per elem), rcp, last-iter reg-only.
// ---------------------------------------------------------------------------
__global__ __launch_bounds__(1024, 2)
void diffuse(const _Float16* __restrict__ f, const float* __restrict__ g,
             float* __restrict__ out,
             const float* __restrict__ bog, const float* __restrict__ bob,
             const float* __restrict__ bom, const float* __restrict__ bov)
{
    __shared__ float B0[ROW], B1[ROW];     // 2 x 32 KB
    const int t = threadIdx.x;
    const int rowb = ((blockIdx.x & 7) << 8) | (blockIdx.x >> 3);  // XCD swizzle
    const int b = rowb >> 7, i = rowb & 127;
    const int im = (i == 0)    ? 1    : i - 1;   // reflect
    const int ip = (i == HH-1) ? HH-2 : i + 1;
    const _Float16* fb  = f + (size_t)b * (HH*ROW);
    const _Float16* frm = fb + (size_t)im * ROW;
    const _Float16* fr0 = fb + (size_t)i  * ROW;
    const _Float16* frp = fb + (size_t)ip * ROW;
    const float* grow = g + (size_t)rowb * ROW;

    const int lane = t & 63;
    const int srcm = (lane & 48) | ((lane - 1) & 15);   // c-group lane-1 (cyclic)
    const int srcp = (lane & 48) | ((lane + 1) & 15);   // c-group lane+1 (cyclic)
    const int w0 = t >> 4, c0 = (t & 15) << 2;
    const int qch[2] = { t*4, t*4 + 4096 };
    const int wch[2] = { w0, w0 + 64 };

    // ---- stage f[i-1]->B0, f[i+1]->B1
    #pragma unroll
    for (int k = 0; k < 2; ++k) {
        half4v vm = *(const half4v*)(frm + qch[k]);
        half4v vp = *(const half4v*)(frp + qch[k]);
        floatx4 a = { (float)vm[0], (float)vm[1], (float)vm[2], (float)vm[3] };
        floatx4 p = { (float)vp[0], (float)vp[1], (float)vp[2], (float)vp[3] };
        *(floatx4*)(B0 + qch[k]) = a;
        *(floatx4*)(B1 + qch[k]) = p;
    }
    __syncthreads();

    // ---- Sobel partials from rows i+-1 (REFLECT in W)
    floatx4 Bx4[2], dxp4[2];
    #pragma unroll
    for (int k = 0; k < 2; ++k) {
        int w = wch[k];
        int wm = (w == 0)    ? 1      : w - 1;
        int wp = (w == WW-1) ? WW - 2 : w + 1;
        floatx4 am = *(const floatx4*)(B0 + wm*CC + c0);
        floatx4 a0 = *(const floatx4*)(B0 + w *CC + c0);
        floatx4 ap = *(const floatx4*)(B0 + wp*CC + c0);
        floatx4 bm = *(const floatx4*)(B1 + wm*CC + c0);
        floatx4 b0 = *(const floatx4*)(B1 + w *CC + c0);
        floatx4 bp = *(const floatx4*)(B1 + wp*CC + c0);
        floatx4 dy = (bm + 2.f*b0 + bp) - (am + 2.f*a0 + ap);
        Bx4[k]  = 0.2f * rcp4(dy*dy*0.25f + 1.f);  // Dx*DT
        dxp4[k] = (ap - am) + (bp - bm);
    }
    __syncthreads();

    // ---- stage f[i]->B0 (= h_0), g->B1
    #pragma unroll
    for (int k = 0; k < 2; ++k) {
        half4v v0 = *(const half4v*)(fr0 + qch[k]);
        floatx4 fv = { (float)v0[0], (float)v0[1], (float)v0[2], (float)v0[3] };
        *(floatx4*)(B0 + qch[k]) = fv;
        *(floatx4*)(B1 + qch[k]) = *(const floatx4*)(grow + qch[k]);
    }
    __syncthreads();

    // ---- coefficients (edge-folded form)
    floatx4 cR4[2], cL4[2], cU4[2], cH0[2], cEE[2], cF[2], h4[2], h04[2];
    #pragma unroll
    for (int k = 0; k < 2; ++k) {
        int w = wch[k];
        int wm = (w == 0)    ? 1      : w - 1;     // reflect (sobel dx)
        int wp = (w == WW-1) ? WW - 2 : w + 1;
        int wl = (w + WW - 1) & (WW - 1);          // cyclic (rolls)
        int wr = (w + 1) & (WW - 1);
        floatx4 fm = *(const floatx4*)(B0 + wm*CC + c0);
        floatx4 fv = *(const floatx4*)(B0 + w *CC + c0);
        floatx4 fp = *(const floatx4*)(B0 + wp*CC + c0);
        floatx4 dx = dxp4[k] + 2.f*(fp - fm);
        floatx4 By = 0.2f * rcp4(dx*dx*0.25f + 1.f);    // Dy*DT
        floatx4 Bx = Bx4[k];
        floatx4 gv = *(const floatx4*)(B1 + w *CC + c0);
        floatx4 gl = *(const floatx4*)(B1 + wl*CC + c0);
        floatx4 gr = *(const floatx4*)(B1 + wr*CC + c0);
        float gdm = __shfl(gv[3], srcm, 64);       // g[c0-1] from lane-1
        float gup = __shfl(gv[0], srcp, 64);       // g[c0+4] from lane+1
        floatx4 gd = { gdm, gv[0], gv[1], gv[2] };
        floatx4 gu = { gv[1], gv[2], gv[3], gup };
        floatx4 E  = ((gl - gr) + (gd - gu)) * 0.1f;     // (ux+vy)*DT
        floatx4 Dd = rcp4(1.f + 2.f*Bx + 2.f*By);
        floatx4 P  = 2.f * Bx * Dd;
        floatx4 R  = 2.f * By * Dd;
        floatx4 Q  = (gv * 0.2f) * Dd;             // g*DT*Dd
        cR4[k] = P + Q;
        cL4[k] = P - Q;
        cU4[k] = R + Q;
        cH0[k] = 2.f*Dd - 1.f;            // == Dd*(1-2Bx-2By)
        cEE[k] = -2.f * E * Dd;
        cF[k]  = 0.4f * Dd * fv;          // Dd * 2*DT*f
        h4[k] = fv; h04[k] = fv;
    }
    __syncthreads();                      // g reads done before loop writes B1

    // loop-invariant LDS offsets (W-direction only; C via shfl)
    int oWl[2], oWr[2];
    #pragma unroll
    for (int k = 0; k < 2; ++k) {
        int w = wch[k];
        oWl[k] = ((w + WW - 1) & (WW - 1))*CC + c0;
        oWr[k] = ((w + 1) & (WW - 1))*CC + c0;
    }

    // ---- K=5 diffusion, h ping-pong B0 -> B1 -> B0 ... (last iter reg-only)
    float* cur = B0;
    float* oth = B1;
    for (int it = 0; it < 5; ++it) {
        #pragma unroll
        for (int k = 0; k < 2; ++k) {
            floatx4 hl = *(const floatx4*)(cur + oWl[k]);
            floatx4 hr = *(const floatx4*)(cur + oWr[k]);
            floatx4 hv = h4[k];
            float hdm = __shfl(hv[3], srcm, 64);
            float hup = __shfl(hv[0], srcp, 64);
            floatx4 hd = { hdm, hv[0], hv[1], hv[2] };
            floatx4 hu = { hv[1], hv[2], hv[3], hup };
            floatx4 cD = (cU4[k] - cR4[k]) + cL4[k];     // R - Q
            floatx4 hn = cH0[k]*h04[k] + cEE[k]*hv
                       + cR4[k]*hr + cL4[k]*hl
                       + cU4[k]*hu + cD*hd + cF[k];
            if (it < 4)
                *(floatx4*)(oth + qch[k]) = hn;
            h04[k] = hv; h4[k] = hn;
        }
        if (it < 4) {
            __syncthreads();
            float* tmp = cur; cur = oth; oth = tmp;
        }
    }

    // ---- epilogue: relu(bn_o(h)) from registers, float4 stores
    floatx4 gg = *(const floatx4*)(bog + c0);
    floatx4 vv = *(const floatx4*)(bov + c0);
    floatx4 bb = *(const floatx4*)(bob + c0);
    floatx4 mm = *(const floatx4*)(bom + c0);
    floatx4 s4, bi4;
    #pragma unroll
    for (int j = 0; j < 4; ++j) s4[j] = gg[j] * rsqrtf(vv[j] + 1e-3f);
    bi4 = bb - mm*s4;
    float* op = out + (size_t)rowb * ROW;
    #pragma unroll
    for (int k = 0; k < 2; ++k) {
        floatx4 rr = h4[k]*s4 + bi4;
        #pragma unroll
        for (int j = 0; j < 4; ++j) rr[j] = fmaxf(0.f, rr[j]);
        *(floatx4*)(op + qch[k]) = rr;
    }
}

// ---------------------------------------------------------------------------
extern "C" void kernel_launch(void* const* d_in, const int* in_sizes, int n_in,
                              void* d_out, int out_size, void* d_ws, size_t ws_size,
                              hipStream_t stream)
{
    const float* x    = (const float*)d_in[0];
    const float* f_w  = (const float*)d_in[1];
    const float* g_w  = (const float*)d_in[2];
    const float* bnf_g = (const float*)d_in[3];
    const float* bnf_b = (const float*)d_in[4];
    const float* bnf_m = (const float*)d_in[5];
    const float* bnf_v = (const float*)d_in[6];
    const float* bng_g = (const float*)d_in[7];
    const float* bng_b = (const float*)d_in[8];
    const float* bng_m = (const float*)d_in[9];
    const float* bng_v = (const float*)d_in[10];
    const float* bno_g = (const float*)d_in[11];
    const float* bno_b = (const float*)d_in[12];
    const float* bno_m = (const float*)d_in[13];
    const float* bno_v = (const float*)d_in[14];

    float* out = (float*)d_out;
    const size_t N = (size_t)16 * HH * WW * CC;   // 16,777,216
    _Float16* y2   = (_Float16*)d_ws;             // N halfs (32 MB), PRE-SWIZZLED
    _Float16* fbuf = y2 + N;                      // N halfs
    _Float16* W2f  = y2 + 2*N;                    // 36864 halfs
    _Float16* W2g  = W2f + 36864;

    repack_w<<<288, 256, 0, stream>>>(f_w, g_w, W2f, W2g);
    // conv1: stage relu(bn_f(x)) inline; write f16 f + fused y2=relu(bn_g(f))
    conv_mfma<1,1><<<1024, 256, 0, stream>>>(x, W2f, fbuf, nullptr, y2,
                                             bnf_g, bnf_b, bnf_m, bnf_v,
                                             bng_g, bng_b, bng_m, bng_v);
    // conv2: global_load_lds staging from swizzled y2; write fp32 g to slot 1
    conv_mfma<0,0><<<1024, 256, 0, stream>>>(y2, W2g, nullptr, out + N, nullptr,
                                             nullptr, nullptr, nullptr, nullptr,
                                             nullptr, nullptr, nullptr, nullptr);
    // diffusion + bn_o + relu -> output slot 0
    diffuse<<<2048, 1024, 0, stream>>>(fbuf, out + N, out, bno_g, bno_b, bno_m, bno_v);
}